// Round 1
// baseline (434.241 us; speedup 1.0000x reference)
//
#include <hip/hip_runtime.h>
#include <cstdint>
#include <cstddef>

#define N_    32
#define C_    256
#define H_    56
#define W_    56
#define HW_   (H_ * W_)      // 3136
#define NHW_  (N_ * HW_)     // 100352
#define COUT_ 256
#define EPS_  1e-4f

// ---------------------------------------------------------------------------
// Kernel 1: BatchNorm batch statistics per channel.
// One block per channel (256 blocks, 256 threads). Reads x coalesced
// (float4), computes sum and sum-of-squares, emits per-channel affine:
//   xn = x * a[c] + bb[c]   where a = gamma*rstd, bb = beta - mu*gamma*rstd
// ---------------------------------------------------------------------------
__global__ void k_bn_stats(const float* __restrict__ x,
                           const float* __restrict__ gamma,
                           const float* __restrict__ beta,
                           float* __restrict__ a, float* __restrict__ bb) {
    const int c = blockIdx.x;
    const int t = threadIdx.x;
    float s = 0.f, sq = 0.f;
    for (int n = 0; n < N_; ++n) {
        const float4* p = (const float4*)(x + (size_t)(n * C_ + c) * HW_);
        for (int i = t; i < HW_ / 4; i += 256) {  // 784 float4 per plane
            float4 v = p[i];
            s  += v.x + v.y + v.z + v.w;
            sq += v.x * v.x + v.y * v.y + v.z * v.z + v.w * v.w;
        }
    }
    __shared__ float ls[256], lq[256];
    ls[t] = s; lq[t] = sq;
    __syncthreads();
    for (int off = 128; off >= 1; off >>= 1) {
        if (t < off) { ls[t] += ls[t + off]; lq[t] += lq[t + off]; }
        __syncthreads();
    }
    if (t == 0) {
        float mu   = ls[0] * (1.f / NHW_);
        float var  = lq[0] * (1.f / NHW_) - mu * mu;
        float rstd = rsqrtf(var + EPS_);
        float g    = gamma[c] * rstd;
        a[c]  = g;
        bb[c] = beta[c] - mu * g;
    }
}

// ---------------------------------------------------------------------------
// Kernel 2: weight prep. One block per cout. alpha = sum|W| / 2304;
// bit-pack sign(W): wbits[co][tap][word], bit i of word wd = (W[co][wd*64+i]>0)
// ---------------------------------------------------------------------------
__global__ void k_wpack(const float* __restrict__ Wt,
                        float* __restrict__ alpha,
                        uint64_t* __restrict__ wbits) {
    const int co = blockIdx.x;
    const int ci = threadIdx.x;                 // 256 threads = 4 waves
    const int lane = ci & 63, wave = ci >> 6;
    const float* p = Wt + (size_t)(co * C_ + ci) * 9;
    float wv[9];
    float asum = 0.f;
#pragma unroll
    for (int t = 0; t < 9; ++t) { wv[t] = p[t]; asum += fabsf(wv[t]); }
#pragma unroll
    for (int t = 0; t < 9; ++t) {
        uint64_t mask = __ballot(wv[t] > 0.f);  // wave64 ballot: 64 channels
        if (lane == 0) wbits[(co * 9 + t) * 4 + wave] = mask;
    }
    __shared__ float red[256];
    red[ci] = asum;
    __syncthreads();
    for (int off = 128; off >= 1; off >>= 1) {
        if (ci < off) red[ci] += red[ci + off];
        __syncthreads();
    }
    if (ci == 0) alpha[co] = red[0] * (1.f / 2304.f);
}

// ---------------------------------------------------------------------------
// Kernel 3: normalize + sign-pack + channel-mean |xn|.
// Block handles one 64-pixel tile of one image (32*49 blocks, 256 threads).
// LDS transpose keeps global reads coalesced; __ballot builds one u64 word
// (64 channels) per pixel per wave.
// ---------------------------------------------------------------------------
__global__ void k_xpack(const float* __restrict__ x,
                        const float* __restrict__ a,
                        const float* __restrict__ bb,
                        uint64_t* __restrict__ xbits,
                        float* __restrict__ m) {
    const int n    = blockIdx.x / 49;
    const int pix0 = (blockIdx.x % 49) * 64;
    const int t    = threadIdx.x;
    const int lane = t & 63, wave = t >> 6;

    __shared__ float tileLS[64][65];   // [c_local][pixel], +1 pad
    __shared__ float msum[64];
    if (t < 64) msum[t] = 0.f;
    __syncthreads();

    for (int wd = 0; wd < 4; ++wd) {
        const int c0 = wd * 64;
        // cooperative coalesced load: 64 channels x 64 pixels
#pragma unroll
        for (int j = 0; j < 16; ++j) {
            int c_l = (t >> 6) + j * 4;
            int p_l = t & 63;
            tileLS[c_l][p_l] = x[(size_t)(n * C_ + c0 + c_l) * HW_ + pix0 + p_l];
        }
        __syncthreads();
        const float av = a[c0 + lane];
        const float bv = bb[c0 + lane];
        // wave handles 16 pixels; lane = channel within word
        for (int pp = 0; pp < 16; ++pp) {
            const int p = wave * 16 + pp;
            float xn = fmaf(tileLS[lane][p], av, bv);
            uint64_t mask = __ballot(xn > 0.f);
            float s = fabsf(xn);
            for (int off = 32; off >= 1; off >>= 1) s += __shfl_down(s, off, 64);
            if (lane == 0) {
                xbits[((size_t)n * HW_ + pix0 + p) * 4 + wd] = mask;
                msum[p] += s;
            }
        }
        __syncthreads();
    }
    if (t < 64) m[(size_t)n * HW_ + pix0 + t] = msum[t] * (1.f / C_);
}

// ---------------------------------------------------------------------------
// Kernel 3b: 3x3 box filter (zero-padded, /9) on m -> beta_map
// ---------------------------------------------------------------------------
__global__ void k_box(const float* __restrict__ m, float* __restrict__ beta_map) {
    const int idx = blockIdx.x * 256 + threadIdx.x;
    if (idx >= NHW_) return;
    const int w = idx % W_;
    const int h = (idx / W_) % H_;
    const int n = idx / HW_;
    const float* mp = m + (size_t)n * HW_;
    float s = 0.f;
#pragma unroll
    for (int dh = 0; dh < 3; ++dh) {
        int ih = h + dh - 1;
        if (ih < 0 || ih >= H_) continue;
#pragma unroll
        for (int dw = 0; dw < 3; ++dw) {
            int iw = w + dw - 1;
            if (iw < 0 || iw >= W_) continue;
            s += mp[ih * W_ + iw];
        }
    }
    beta_map[idx] = s * (1.f / 9.f);
}

// ---------------------------------------------------------------------------
// Kernel 4: binary conv via XNOR-popcount + fused epilogue.
// Block = (n, h) (1792 blocks); thread = cout (256). All xbits/beta_map
// addresses are wave-uniform -> scalar loads. Weight words (36 x u64) live
// in VGPRs. dot = 256*nvalid - 2*sum(popc(x^w)); out = relu((dot+b)*beta*alpha).
// ---------------------------------------------------------------------------
__global__ void __launch_bounds__(256)
k_conv(const uint64_t* __restrict__ xbits,
       const uint64_t* __restrict__ wbits,
       const float* __restrict__ beta_map,
       const float* __restrict__ alpha,
       const float* __restrict__ bias,
       float* __restrict__ out) {
    const int nh = blockIdx.x;
    const int n = nh / H_;
    const int h = nh % H_;
    const int co = threadIdx.x;

    uint64_t wreg[9][4];
    {
        const uint64_t* wp = wbits + (size_t)co * 36;
#pragma unroll
        for (int i = 0; i < 36; ++i) ((uint64_t*)wreg)[i] = wp[i];
    }
    const float al = alpha[co];
    const float bv = bias[co];
    const uint64_t* xrow = xbits + (size_t)n * HW_ * 4;
    const float*    brow = beta_map + (size_t)n * HW_ + h * W_;
    float*          orow = out + ((size_t)(n * COUT_ + co) * H_ + h) * W_;

    for (int w4 = 0; w4 < 14; ++w4) {
        float ov[4];
#pragma unroll
        for (int k = 0; k < 4; ++k) {
            const int w = w4 * 4 + k;
            int acc = 0;
            int nvalid = 0;
#pragma unroll
            for (int dh = 0; dh < 3; ++dh) {
                const int ih = h + dh - 1;
                const bool rowok = (ih >= 0) && (ih < H_);
#pragma unroll
                for (int dw = 0; dw < 3; ++dw) {
                    const int iw = w + dw - 1;
                    if (rowok && iw >= 0 && iw < W_) {   // uniform branch
                        const uint64_t* xp = xrow + ((size_t)ih * W_ + iw) * 4;
#pragma unroll
                        for (int wd = 0; wd < 4; ++wd)
                            acc += __popcll(xp[wd] ^ wreg[dh * 3 + dw][wd]);
                        nvalid++;
                    }
                }
            }
            const int dot = 256 * nvalid - 2 * acc;
            float o = ((float)dot + bv) * brow[w] * al;
            ov[k] = fmaxf(o, 0.f);
        }
        ((float4*)orow)[w4] = make_float4(ov[0], ov[1], ov[2], ov[3]);
    }
}

// ---------------------------------------------------------------------------
// Workspace layout (bytes):
//   a        @ 0        1024
//   bb       @ 1024     1024
//   alpha    @ 2048     1024
//   wbits    @ 4096     73728
//   xbits    @ 77824    3211264
//   m        @ 3289088  401408
//   beta_map @ 3690496  401408
//   total    4091904
// ---------------------------------------------------------------------------
extern "C" void kernel_launch(void* const* d_in, const int* in_sizes, int n_in,
                              void* d_out, int out_size, void* d_ws, size_t ws_size,
                              hipStream_t stream) {
    (void)in_sizes; (void)n_in; (void)out_size; (void)ws_size;
    const float* x     = (const float*)d_in[0];
    const float* gamma = (const float*)d_in[1];
    const float* betab = (const float*)d_in[2];
    const float* Wt    = (const float*)d_in[3];
    const float* b     = (const float*)d_in[4];
    float* out = (float*)d_out;

    uint8_t* base = (uint8_t*)d_ws;
    float*    a        = (float*)(base + 0);
    float*    bb       = (float*)(base + 1024);
    float*    alpha    = (float*)(base + 2048);
    uint64_t* wbits    = (uint64_t*)(base + 4096);
    uint64_t* xbits    = (uint64_t*)(base + 77824);
    float*    m        = (float*)(base + 3289088);
    float*    beta_map = (float*)(base + 3690496);

    k_bn_stats<<<C_, 256, 0, stream>>>(x, gamma, betab, a, bb);
    k_wpack<<<COUT_, 256, 0, stream>>>(Wt, alpha, wbits);
    k_xpack<<<N_ * 49, 256, 0, stream>>>(x, a, bb, xbits, m);
    k_box<<<(NHW_ + 255) / 256, 256, 0, stream>>>(m, beta_map);
    k_conv<<<N_ * H_, 256, 0, stream>>>(xbits, wbits, beta_map, alpha, b, out);
}

// Round 2
// 369.394 us; speedup vs baseline: 1.1755x; 1.1755x over previous
//
#include <hip/hip_runtime.h>
#include <cstdint>
#include <cstddef>

#define N_    32
#define C_    256
#define H_    56
#define W_    56
#define HW_   (H_ * W_)      // 3136
#define NHW_  (N_ * HW_)     // 100352
#define COUT_ 256
#define EPS_  1e-4f

// ---------------------------------------------------------------------------
// Kernel 1a: BN partial sums. 2048 blocks = (c, slice of 4 images).
// ---------------------------------------------------------------------------
__global__ void k_bn_partial(const float* __restrict__ x,
                             float* __restrict__ ps, float* __restrict__ pq) {
    const int c = blockIdx.x >> 3;
    const int s = blockIdx.x & 7;
    const int t = threadIdx.x;
    float sm = 0.f, sq = 0.f;
    for (int n = s * 4; n < s * 4 + 4; ++n) {
        const float4* p = (const float4*)(x + (size_t)(n * C_ + c) * HW_);
        for (int i = t; i < HW_ / 4; i += 256) {
            float4 v = p[i];
            sm += v.x + v.y + v.z + v.w;
            sq += v.x * v.x + v.y * v.y + v.z * v.z + v.w * v.w;
        }
    }
    __shared__ float ls[256], lq[256];
    ls[t] = sm; lq[t] = sq;
    __syncthreads();
    for (int off = 128; off >= 1; off >>= 1) {
        if (t < off) { ls[t] += ls[t + off]; lq[t] += lq[t + off]; }
        __syncthreads();
    }
    if (t == 0) { ps[s * C_ + c] = ls[0]; pq[s * C_ + c] = lq[0]; }
}

// ---------------------------------------------------------------------------
// Kernel 1b: finalize per-channel affine: xn = x*a[c] + bb[c]
// ---------------------------------------------------------------------------
__global__ void k_bn_final(const float* __restrict__ ps, const float* __restrict__ pq,
                           const float* __restrict__ gamma, const float* __restrict__ beta,
                           float* __restrict__ a, float* __restrict__ bb) {
    const int c = threadIdx.x;
    float sm = 0.f, sq = 0.f;
    for (int s = 0; s < 8; ++s) { sm += ps[s * C_ + c]; sq += pq[s * C_ + c]; }
    float mu   = sm * (1.f / NHW_);
    float var  = sq * (1.f / NHW_) - mu * mu;
    float rstd = rsqrtf(var + EPS_);
    float g    = gamma[c] * rstd;
    a[c]  = g;
    bb[c] = beta[c] - mu * g;
}

// ---------------------------------------------------------------------------
// Kernel 2: weight prep. alpha, bit-pack sign(W), per-tap popcounts P[t].
// wbits[co][tap][word]; wpopc[co*12 + t] = popcount over 256 ch of tap t.
// ---------------------------------------------------------------------------
__global__ void k_wpack(const float* __restrict__ Wt, float* __restrict__ alpha,
                        uint64_t* __restrict__ wbits, int* __restrict__ wpopc) {
    const int co = blockIdx.x;
    const int ci = threadIdx.x;
    const int lane = ci & 63, wave = ci >> 6;
    const float* p = Wt + (size_t)(co * C_ + ci) * 9;
    float wv[9];
    float asum = 0.f;
#pragma unroll
    for (int t = 0; t < 9; ++t) { wv[t] = p[t]; asum += fabsf(wv[t]); }
    __shared__ int Pl[9];
    if (ci < 9) Pl[ci] = 0;
    __syncthreads();
#pragma unroll
    for (int t = 0; t < 9; ++t) {
        uint64_t mask = __ballot(wv[t] > 0.f);
        if (lane == 0) {
            wbits[(co * 9 + t) * 4 + wave] = mask;
            atomicAdd(&Pl[t], (int)__popcll(mask));
        }
    }
    __shared__ float red[256];
    red[ci] = asum;
    __syncthreads();
    for (int off = 128; off >= 1; off >>= 1) {
        if (ci < off) red[ci] += red[ci + off];
        __syncthreads();
    }
    if (ci == 0) alpha[co] = red[0] * (1.f / 2304.f);
    if (ci < 9) wpopc[co * 12 + ci] = Pl[ci];
}

// ---------------------------------------------------------------------------
// Kernel 3: fused normalize + |xn| channel-mean + sign bit-pack.
// lane = pixel (coalesced). Fully unrolled c-loop: constant shifts, no LDS,
// no shuffles. bits[wd] bit j = sign(xn[wd*64+j]) > 0.
// ---------------------------------------------------------------------------
__global__ void k_mpack(const float* __restrict__ x, const float* __restrict__ a,
                        const float* __restrict__ bb, uint64_t* __restrict__ xbits,
                        float* __restrict__ m) {
    const int p = blockIdx.x * 256 + threadIdx.x;
    const int n = p / HW_;
    const int hw = p - n * HW_;
    const float* xp = x + (size_t)n * C_ * HW_ + hw;
    float macc = 0.f;
    uint64_t bits[4];
#pragma unroll
    for (int wd = 0; wd < 4; ++wd) {
        uint64_t bw = 0;
#pragma unroll
        for (int j = 0; j < 64; ++j) {
            const int c = wd * 64 + j;
            float xn = fmaf(xp[(size_t)c * HW_], a[c], bb[c]);
            macc += fabsf(xn);
            bw |= (xn > 0.f) ? (1ull << j) : 0ull;
        }
        bits[wd] = bw;
    }
    ulonglong2* xb = (ulonglong2*)(xbits + (size_t)p * 4);
    xb[0] = make_ulonglong2(bits[0], bits[1]);
    xb[1] = make_ulonglong2(bits[2], bits[3]);
    m[p] = macc * (1.f / C_);
}

// ---------------------------------------------------------------------------
// Kernel 3b: 3x3 box filter (zero-padded, /9) on m -> beta_map
// ---------------------------------------------------------------------------
__global__ void k_box(const float* __restrict__ m, float* __restrict__ beta_map) {
    const int idx = blockIdx.x * 256 + threadIdx.x;
    if (idx >= NHW_) return;
    const int w = idx % W_;
    const int h = (idx / W_) % H_;
    const int n = idx / HW_;
    const float* mp = m + (size_t)n * HW_;
    float s = 0.f;
#pragma unroll
    for (int dh = 0; dh < 3; ++dh) {
        int ih = h + dh - 1;
        if (ih < 0 || ih >= H_) continue;
#pragma unroll
        for (int dw = 0; dw < 3; ++dw) {
            int iw = w + dw - 1;
            if (iw < 0 || iw >= W_) continue;
            s += mp[ih * W_ + iw];
        }
    }
    beta_map[idx] = s * (1.f / 9.f);
}

// ---------------------------------------------------------------------------
// Kernel 4: binary conv, transposed mapping.
// Block = (n, h); lane = w (coalesced stores); wave loops 64 couts.
// x window (9 taps x 4 words) in VGPRs, loaded once and reused 64x.
// Weights wave-uniform -> SGPRs. Border taps: x word zeroed, corrected via
// precomputed per-tap weight popcounts:
//   dot = 256*nvalid - 2*acc + 2*(Ptot - sum_{valid cols} colsum)
// ---------------------------------------------------------------------------
__global__ void __launch_bounds__(256)
k_conv(const uint64_t* __restrict__ xbits, const uint64_t* __restrict__ wbits,
       const int* __restrict__ wpopc,
       const float* __restrict__ beta_map, const float* __restrict__ alpha,
       const float* __restrict__ bias, float* __restrict__ out) {
    const int nh = blockIdx.x;
    const int n = nh / H_, h = nh % H_;
    const int lane = (int)(threadIdx.x & 63);
    const int wv = __builtin_amdgcn_readfirstlane((int)(threadIdx.x >> 6));
    const int w = lane;
    const bool r0 = (h > 0), r2 = (h < H_ - 1);

    bool cok0 = (w >= 1) && (w < W_);
    bool cok1 = (w < W_);
    bool cok2 = (w < W_ - 1);
    const int nvalid = (1 + (int)r0 + (int)r2) * ((int)cok0 + (int)cok1 + (int)cok2);

    // x window: 9 taps x 4 u64 words, in VGPRs, invalid taps zeroed
    uint64_t xw[9][4];
    const uint64_t* xim = xbits + (size_t)n * HW_ * 4;
#pragma unroll
    for (int dh = 0; dh < 3; ++dh) {
        const bool rok = (dh == 0) ? r0 : (dh == 2) ? r2 : true;
        int ih = h + dh - 1;
        ih = ih < 0 ? 0 : (ih > H_ - 1 ? H_ - 1 : ih);
#pragma unroll
        for (int dw = 0; dw < 3; ++dw) {
            const bool cok = (dw == 0) ? cok0 : (dw == 2) ? cok2 : cok1;
            int iw = w + dw - 1;
            iw = iw < 0 ? 0 : (iw > W_ - 1 ? W_ - 1 : iw);
            const uint64_t* xp = xim + ((size_t)ih * W_ + iw) * 4;
            const bool ok = rok && cok;
#pragma unroll
            for (int wd = 0; wd < 4; ++wd)
                xw[dh * 3 + dw][wd] = ok ? xp[wd] : 0ull;
        }
    }

    const float bm = (w < W_) ? beta_map[(size_t)n * HW_ + (size_t)h * W_ + w] : 0.f;
    float* obase = out + (size_t)n * COUT_ * HW_ + (size_t)h * W_;

    for (int coi = 0; coi < 64; ++coi) {
        const int co = wv * 64 + coi;
        const uint64_t* wq = wbits + (size_t)co * 36;
        const int* pq = wpopc + co * 12;

        int acc0 = 0, acc1 = 0, acc2 = 0, acc3 = 0;
#pragma unroll
        for (int t = 0; t < 9; ++t) {
            acc0 += __popcll(xw[t][0] ^ wq[t * 4 + 0]);
            acc1 += __popcll(xw[t][1] ^ wq[t * 4 + 1]);
            acc2 += __popcll(xw[t][2] ^ wq[t * 4 + 2]);
            acc3 += __popcll(xw[t][3] ^ wq[t * 4 + 3]);
        }
        const int acc = (acc0 + acc1) + (acc2 + acc3);

        int P[9], Ptot = 0;
#pragma unroll
        for (int t = 0; t < 9; ++t) { P[t] = pq[t]; Ptot += P[t]; }
        const int cs0 = (r0 ? P[0] : 0) + P[3] + (r2 ? P[6] : 0);
        const int cs1 = (r0 ? P[1] : 0) + P[4] + (r2 ? P[7] : 0);
        const int cs2 = (r0 ? P[2] : 0) + P[5] + (r2 ? P[8] : 0);
        const int sumv = (cok0 ? cs0 : 0) + (cok1 ? cs1 : 0) + (cok2 ? cs2 : 0);
        const int corr = Ptot - sumv;

        const int dot = 256 * nvalid - 2 * acc + 2 * corr;
        float o = ((float)dot + bias[co]) * bm * alpha[co];
        o = fmaxf(o, 0.f);
        if (w < W_) obase[(size_t)co * HW_ + w] = o;
    }
}

// ---------------------------------------------------------------------------
// Workspace layout (bytes):
//   ps       @ 0        8192
//   pq       @ 8192     8192
//   a        @ 16384    1024
//   bb       @ 17408    1024
//   alpha    @ 18432    1024
//   wpopc    @ 19456    12288
//   wbits    @ 31744    73728
//   xbits    @ 105472   3211264
//   m        @ 3316736  401408
//   beta_map @ 3718144  401408
//   total    4119552
// ---------------------------------------------------------------------------
extern "C" void kernel_launch(void* const* d_in, const int* in_sizes, int n_in,
                              void* d_out, int out_size, void* d_ws, size_t ws_size,
                              hipStream_t stream) {
    (void)in_sizes; (void)n_in; (void)out_size; (void)ws_size;
    const float* x     = (const float*)d_in[0];
    const float* gamma = (const float*)d_in[1];
    const float* betab = (const float*)d_in[2];
    const float* Wt    = (const float*)d_in[3];
    const float* b     = (const float*)d_in[4];
    float* out = (float*)d_out;

    uint8_t* base = (uint8_t*)d_ws;
    float*    ps       = (float*)(base + 0);
    float*    pq       = (float*)(base + 8192);
    float*    a        = (float*)(base + 16384);
    float*    bb       = (float*)(base + 17408);
    float*    alpha    = (float*)(base + 18432);
    int*      wpopc    = (int*)(base + 19456);
    uint64_t* wbits    = (uint64_t*)(base + 31744);
    uint64_t* xbits    = (uint64_t*)(base + 105472);
    float*    m        = (float*)(base + 3316736);
    float*    beta_map = (float*)(base + 3718144);

    k_bn_partial<<<2048, 256, 0, stream>>>(x, ps, pq);
    k_bn_final<<<1, 256, 0, stream>>>(ps, pq, gamma, betab, a, bb);
    k_wpack<<<COUT_, 256, 0, stream>>>(Wt, alpha, wbits, wpopc);
    k_mpack<<<NHW_ / 256, 256, 0, stream>>>(x, a, bb, xbits, m);
    k_box<<<(NHW_ + 255) / 256, 256, 0, stream>>>(m, beta_map);
    k_conv<<<N_ * H_, 256, 0, stream>>>(xbits, wbits, wpopc, beta_map, alpha, b, out);
}

// Round 3
// 337.021 us; speedup vs baseline: 1.2885x; 1.0961x over previous
//
#include <hip/hip_runtime.h>
#include <cstdint>
#include <cstddef>

#define N_    32
#define C_    256
#define H_    56
#define W_    56
#define HW_   (H_ * W_)      // 3136
#define NHW_  (N_ * HW_)     // 100352
#define COUT_ 256
#define EPS_  1e-4f
#define PW_   58             // padded width
#define PIMG_ (PW_ * PW_)    // 3364 padded pixels per image

// ---------------------------------------------------------------------------
// Kernel 1a: BN partial sums. 2048 blocks = (c, slice of 4 images).
// ---------------------------------------------------------------------------
__global__ void k_bn_partial(const float* __restrict__ x,
                             float* __restrict__ ps, float* __restrict__ pq) {
    const int c = blockIdx.x >> 3;
    const int s = blockIdx.x & 7;
    const int t = threadIdx.x;
    float sm = 0.f, sq = 0.f;
    for (int n = s * 4; n < s * 4 + 4; ++n) {
        const float4* p = (const float4*)(x + (size_t)(n * C_ + c) * HW_);
        for (int i = t; i < HW_ / 4; i += 256) {
            float4 v = p[i];
            sm += v.x + v.y + v.z + v.w;
            sq += v.x * v.x + v.y * v.y + v.z * v.z + v.w * v.w;
        }
    }
    __shared__ float ls[256], lq[256];
    ls[t] = sm; lq[t] = sq;
    __syncthreads();
    for (int off = 128; off >= 1; off >>= 1) {
        if (t < off) { ls[t] += ls[t + off]; lq[t] += lq[t + off]; }
        __syncthreads();
    }
    if (t == 0) { ps[s * C_ + c] = ls[0]; pq[s * C_ + c] = lq[0]; }
}

// ---------------------------------------------------------------------------
// Kernel 1b: finalize per-channel affine: xn = x*a[c] + bb[c]
// ---------------------------------------------------------------------------
__global__ void k_bn_final(const float* __restrict__ ps, const float* __restrict__ pq,
                           const float* __restrict__ gamma, const float* __restrict__ beta,
                           float* __restrict__ a, float* __restrict__ bb) {
    const int c = threadIdx.x;
    float sm = 0.f, sq = 0.f;
    for (int s = 0; s < 8; ++s) { sm += ps[s * C_ + c]; sq += pq[s * C_ + c]; }
    float mu   = sm * (1.f / NHW_);
    float var  = sq * (1.f / NHW_) - mu * mu;
    float rstd = rsqrtf(var + EPS_);
    float g    = gamma[c] * rstd;
    a[c]  = g;
    bb[c] = beta[c] - mu * g;
}

// ---------------------------------------------------------------------------
// Kernel 2: weight prep. alpha, bit-pack sign(W), and border-correction table
// ctab[cls][co] = sum over invalid taps of (2*P[t] - 256), cls = rowcls*3+colcls.
// With zero-padded xbits, dot = 2304 - 2*acc + ctab[cls][co].
// ---------------------------------------------------------------------------
__global__ void k_wpack(const float* __restrict__ Wt, float* __restrict__ alpha,
                        uint64_t* __restrict__ wbits, int* __restrict__ ctab) {
    const int co = blockIdx.x;
    const int ci = threadIdx.x;
    const int lane = ci & 63, wave = ci >> 6;
    const float* p = Wt + (size_t)(co * C_ + ci) * 9;
    float wv[9];
    float asum = 0.f;
#pragma unroll
    for (int t = 0; t < 9; ++t) { wv[t] = p[t]; asum += fabsf(wv[t]); }
    __shared__ int Pl[9];
    if (ci < 9) Pl[ci] = 0;
    __syncthreads();
#pragma unroll
    for (int t = 0; t < 9; ++t) {
        uint64_t mask = __ballot(wv[t] > 0.f);
        if (lane == 0) {
            wbits[(co * 9 + t) * 4 + wave] = mask;
            atomicAdd(&Pl[t], (int)__popcll(mask));
        }
    }
    __shared__ float red[256];
    red[ci] = asum;
    __syncthreads();                       // also publishes Pl
    for (int off = 128; off >= 1; off >>= 1) {
        if (ci < off) red[ci] += red[ci + off];
        __syncthreads();
    }
    if (ci == 0) alpha[co] = red[0] * (1.f / 2304.f);
    if (ci < 9) {
        const int rc = ci / 3, cc = ci % 3;
        unsigned m9 = (rc == 0 ? 0x007u : 0u) | (rc == 2 ? 0x1C0u : 0u)
                    | (cc == 0 ? 0x049u : 0u) | (cc == 2 ? 0x124u : 0u);
        int s = 0;
#pragma unroll
        for (int t = 0; t < 9; ++t)
            if ((m9 >> t) & 1) s += 2 * Pl[t] - 256;
        ctab[ci * 256 + co] = s;
    }
}

// ---------------------------------------------------------------------------
// Kernel 3: fused normalize + |xn| channel-mean + sign bit-pack into PADDED
// layout (58x58 per image, border pre-zeroed by memset).
// ---------------------------------------------------------------------------
__global__ void k_mpack(const float* __restrict__ x, const float* __restrict__ a,
                        const float* __restrict__ bb, uint64_t* __restrict__ xbits,
                        float* __restrict__ m) {
    const int p = blockIdx.x * 256 + threadIdx.x;
    const int n = p / HW_;
    const int hw = p - n * HW_;
    const int h = hw / W_;
    const int w = hw - h * W_;
    const float* xp = x + (size_t)n * C_ * HW_ + hw;
    float macc = 0.f;
    uint64_t bits[4];
#pragma unroll
    for (int wd = 0; wd < 4; ++wd) {
        uint64_t bw = 0;
#pragma unroll
        for (int j = 0; j < 64; ++j) {
            const int c = wd * 64 + j;
            float xn = fmaf(xp[(size_t)c * HW_], a[c], bb[c]);
            macc += fabsf(xn);
            bw |= (xn > 0.f) ? (1ull << j) : 0ull;
        }
        bits[wd] = bw;
    }
    ulonglong2* xb = (ulonglong2*)(xbits + ((size_t)n * PIMG_ + (size_t)(h + 1) * PW_ + (w + 1)) * 4);
    xb[0] = make_ulonglong2(bits[0], bits[1]);
    xb[1] = make_ulonglong2(bits[2], bits[3]);
    m[p] = macc * (1.f / C_);
}

// ---------------------------------------------------------------------------
// Kernel 3b: 3x3 box filter (zero-padded, /9) on m -> beta_map
// ---------------------------------------------------------------------------
__global__ void k_box(const float* __restrict__ m, float* __restrict__ beta_map) {
    const int idx = blockIdx.x * 256 + threadIdx.x;
    if (idx >= NHW_) return;
    const int w = idx % W_;
    const int h = (idx / W_) % H_;
    const int n = idx / HW_;
    const float* mp = m + (size_t)n * HW_;
    float s = 0.f;
#pragma unroll
    for (int dh = 0; dh < 3; ++dh) {
        int ih = h + dh - 1;
        if (ih < 0 || ih >= H_) continue;
#pragma unroll
        for (int dw = 0; dw < 3; ++dw) {
            int iw = w + dw - 1;
            if (iw < 0 || iw >= W_) continue;
            s += mp[ih * W_ + iw];
        }
    }
    beta_map[idx] = s * (1.f / 9.f);
}

// ---------------------------------------------------------------------------
// Kernel 4: binary conv. lane = flat pixel (coalesced loads+stores, 100%
// lane use), grid.y = cout group of 64. x window (36 u64 = 72 VGPRs) loaded
// ONCE from padded xbits with const immediate offsets and held in registers
// (__launch_bounds__(256,4) -> 128 VGPR budget). Weights wave-uniform ->
// s_load. Border handled by zero padding + ctab correction.
// ---------------------------------------------------------------------------
__global__ void __launch_bounds__(256, 4)
k_conv(const uint64_t* __restrict__ xbits, const uint64_t* __restrict__ wbits,
       const int* __restrict__ ctab, const float* __restrict__ beta_map,
       const float* __restrict__ alpha, const float* __restrict__ bias,
       float* __restrict__ out) {
    const int p   = blockIdx.x * 256 + (int)threadIdx.x;  // flat pixel
    const int grp = blockIdx.y;                            // cout group
    const int n  = p / HW_;
    const int hw = p - n * HW_;
    const int h  = hw / W_;
    const int w  = hw - h * W_;

    // load 3x3 x-window (4 u64 words each) into registers, branch-free
    const uint64_t* xb = xbits + ((size_t)n * PIMG_ + (size_t)h * PW_ + w) * 4;
    uint64_t xw[36];
#pragma unroll
    for (int dh = 0; dh < 3; ++dh)
#pragma unroll
        for (int dw = 0; dw < 3; ++dw) {
            const uint64_t* tp = xb + ((size_t)dh * PW_ + dw) * 4;
#pragma unroll
            for (int wd = 0; wd < 4; ++wd)
                xw[(dh * 3 + dw) * 4 + wd] = tp[wd];
        }

    const int rowcls = (h == 0) ? 0 : ((h == H_ - 1) ? 2 : 1);
    const int colcls = (w == 0) ? 0 : ((w == W_ - 1) ? 2 : 1);
    const int* crow = ctab + (rowcls * 3 + colcls) * 256 + grp * 64;

    const float bm = beta_map[p];
    float* op = out + (size_t)n * COUT_ * HW_ + (size_t)(grp * 64) * HW_ + hw;

    for (int coi = 0; coi < 64; ++coi) {
        const int co = grp * 64 + coi;
        const uint64_t* wq = wbits + (size_t)co * 36;
        int a0 = 0, a1 = 0, a2 = 0, a3 = 0;
#pragma unroll
        for (int t = 0; t < 9; ++t) {
            a0 += __popcll(xw[t * 4 + 0] ^ wq[t * 4 + 0]);
            a1 += __popcll(xw[t * 4 + 1] ^ wq[t * 4 + 1]);
            a2 += __popcll(xw[t * 4 + 2] ^ wq[t * 4 + 2]);
            a3 += __popcll(xw[t * 4 + 3] ^ wq[t * 4 + 3]);
        }
        const int acc = (a0 + a1) + (a2 + a3);
        const int dot = 2304 - 2 * acc + crow[coi];
        float o = ((float)dot + bias[co]) * bm * alpha[co];
        o = fmaxf(o, 0.f);
        op[(size_t)coi * HW_] = o;
    }
}

// ---------------------------------------------------------------------------
// Workspace layout (bytes):
//   ps       @ 0        8192
//   pq       @ 8192     8192
//   a        @ 16384    1024
//   bb       @ 17408    1024
//   alpha    @ 18432    1024
//   ctab     @ 19456    9216
//   wbits    @ 28672    73728
//   xbits    @ 102400   3444736   (32 * 58*58 * 4 u64, zeroed via memset)
//   m        @ 3547136  401408
//   beta_map @ 3948544  401408
//   total    4349952
// ---------------------------------------------------------------------------
extern "C" void kernel_launch(void* const* d_in, const int* in_sizes, int n_in,
                              void* d_out, int out_size, void* d_ws, size_t ws_size,
                              hipStream_t stream) {
    (void)in_sizes; (void)n_in; (void)out_size; (void)ws_size;
    const float* x     = (const float*)d_in[0];
    const float* gamma = (const float*)d_in[1];
    const float* betab = (const float*)d_in[2];
    const float* Wt    = (const float*)d_in[3];
    const float* b     = (const float*)d_in[4];
    float* out = (float*)d_out;

    uint8_t* base = (uint8_t*)d_ws;
    float*    ps       = (float*)(base + 0);
    float*    pq       = (float*)(base + 8192);
    float*    a        = (float*)(base + 16384);
    float*    bb       = (float*)(base + 17408);
    float*    alpha    = (float*)(base + 18432);
    int*      ctab     = (int*)(base + 19456);
    uint64_t* wbits    = (uint64_t*)(base + 28672);
    uint64_t* xbits    = (uint64_t*)(base + 102400);
    float*    m        = (float*)(base + 3547136);
    float*    beta_map = (float*)(base + 3948544);

    k_bn_partial<<<2048, 256, 0, stream>>>(x, ps, pq);
    k_bn_final<<<1, 256, 0, stream>>>(ps, pq, gamma, betab, a, bb);
    k_wpack<<<COUT_, 256, 0, stream>>>(Wt, alpha, wbits, ctab);
    hipMemsetAsync(xbits, 0, (size_t)N_ * PIMG_ * 4 * sizeof(uint64_t), stream);
    k_mpack<<<NHW_ / 256, 256, 0, stream>>>(x, a, bb, xbits, m);
    k_box<<<(NHW_ + 255) / 256, 256, 0, stream>>>(m, beta_map);
    k_conv<<<dim3(NHW_ / 256, 4), 256, 0, stream>>>(xbits, wbits, ctab, beta_map, alpha, b, out);
}